// Round 8
// baseline (116.780 us; speedup 1.0000x reference)
//
#include <hip/hip_runtime.h>
#include <math.h>

#define NREL  32
#define NENT  2048
#define NATTR 8
#define WIDTH 256
#define NK    (2 * NREL + NATTR)   // 72
#define CHUNKS_OUT 16              // partial rows per relation
#define SUBS  4                    // sub-chunks (32 rows) per block

typedef float f4 __attribute__((ext_vector_type(4)));

// ---------------------------------------------------------------------------
// Kernel A: one pass over database — BYTE-IDENTICAL to the 100.2us R7 kernel.
// Non-temporal db reads (zero-reuse 512MB stream), row sums via transposed
// LDS, acc[8] column partials in registers -> partial[bx].
// ---------------------------------------------------------------------------
__global__ __launch_bounds__(256) void reduce_db_kernel(
    const float* __restrict__ db,
    float* __restrict__ qout,        // quantified region [72][2048]
    float* __restrict__ partial,     // [NREL*CHUNKS_OUT][2048]
    int rowsPerWave,                 // = 8  (runtime)
    int nSubs)                       // = 4  (runtime)
{
    const int bx   = blockIdx.x;
    const int r    = bx >> 4;              // / CHUNKS_OUT
    const int cOut = bx & (CHUNKS_OUT - 1);
    const int tid  = threadIdx.x;
    const int wave = tid >> 6;
    const int lane = tid & 63;

    __shared__ __align__(16) float smem[4][NENT];        // 32KB, dual-purpose
    float (*rpart)[33] = reinterpret_cast<float(*)[33]>(&smem[0][0]); // [64][33]

    const size_t rowStride = NENT / 4;
    const f4* relBase = reinterpret_cast<const f4*>(db)
                      + (size_t)r * NENT * rowStride
                      + (size_t)(cOut * 128) * rowStride
                      + lane;

    f4 acc[8];
#pragma unroll
    for (int k = 0; k < 8; ++k) acc[k] = (f4)0.f;

    for (int sc = 0; sc < nSubs; ++sc) {
        const int i0 = sc * 32;                  // local row base
        const f4* base = relBase
                       + (size_t)(i0 + wave * rowsPerWave) * rowStride;

        for (int j = 0; j < rowsPerWave; j += 2) {
            const f4* rowA = base + (size_t)j * rowStride;
            const f4* rowB = rowA + rowStride;
            float rsA = 0.f, rsB = 0.f;
            // 16 independent NON-TEMPORAL float4 loads; no cross-lane ops
#pragma unroll
            for (int k = 0; k < 8; ++k) {
                f4 v = __builtin_nontemporal_load(rowA + k * 64);
                acc[k] += v;
                rsA += (v.x + v.y) + (v.z + v.w);
            }
#pragma unroll
            for (int k = 0; k < 8; ++k) {
                f4 v = __builtin_nontemporal_load(rowB + k * 64);
                acc[k] += v;
                rsB += (v.x + v.y) + (v.z + v.w);
            }
            rpart[lane][wave * rowsPerWave + j]     = rsA;
            rpart[lane][wave * rowsPerWave + j + 1] = rsB;
        }
        __syncthreads();

        // finish row sums for this sub-chunk: thread t -> (row, 8-lane seg)
        {
            const int row = tid >> 3;       // 0..31 (local)
            const int seg = tid & 7;
            float t = 0.f;
#pragma unroll
            for (int i = 0; i < 8; ++i) t += rpart[seg * 8 + i][row];
            t += __shfl_xor(t, 1, 64);
            t += __shfl_xor(t, 2, 64);
            t += __shfl_xor(t, 4, 64);
            if (seg == 0)
                qout[(size_t)(NREL + r) * NENT + cOut * 128 + i0 + row] =
                    1.f - __expf(-t);
        }
        __syncthreads();   // rpart reads done before next sub-chunk rewrites
    }

    // block epilogue: combine the 4 waves' column partials (overlay rpart)
#pragma unroll
    for (int k = 0; k < 8; ++k)
        *reinterpret_cast<f4*>(&smem[wave][k * 256 + lane * 4]) = acc[k];
    __syncthreads();

    f4* part4 = reinterpret_cast<f4*>(partial) + (size_t)bx * rowStride;
    for (int g = tid; g < NENT / 4; g += 256) {
        f4 a0 = *reinterpret_cast<const f4*>(&smem[0][g * 4]);
        f4 a1 = *reinterpret_cast<const f4*>(&smem[1][g * 4]);
        f4 a2 = *reinterpret_cast<const f4*>(&smem[2][g * 4]);
        f4 a3 = *reinterpret_cast<const f4*>(&smem[3][g * 4]);
        part4[g] = (a0 + a1) + (a2 + a3);
    }
}

// ---------------------------------------------------------------------------
// Kernel BC (merged tail, depends ONLY on A):
//  blocks 0..31   : matmul. Block b owns cols [b*64, b*64+64) x ALL 256 w's.
//                   Self-finalizes quant rows 0..31 from `partial` into LDS
//                   (32 blocks x 128KB = 4MB total, no redundancy), rows
//                   32..63 from A's qout, rows 64..71 from attrs. Per-thread
//                   softmax (thread = w). k-loop LDS reads are all-lane
//                   broadcasts (conflict-free). No sw workspace.
//  blocks 32..351 : finalize quantified output rows 0..31 (16-chunk sums)
//                   and attribute rows 64..71 (same as old kernel B).
// ---------------------------------------------------------------------------
#define MM_BLOCKS  (NENT / 64)                     // 32
#define FIN_BLOCKS ((NREL + NATTR) * NENT / 256)   // 320

__global__ __launch_bounds__(256) void tail_kernel(
    const float* __restrict__ partial,
    const float* __restrict__ attrs,
    const float* __restrict__ W,
    float* __restrict__ qout,
    float* __restrict__ out)
{
    const int b   = blockIdx.x;
    const int tid = threadIdx.x;

    if (b < MM_BLOCKS) {
        // ---------------- matmul block: 64-col slice, all 256 w ----------
        __shared__ __align__(16) float qt[NK][68];   // 68-pad, rows 16B aligned
        const int c0  = b * 64;                      // first col of slice
        const int cq  = c0 >> 2;                     // first f4 of slice
        const f4* part4  = reinterpret_cast<const f4*>(partial);
        const f4* qout4  = reinterpret_cast<const f4*>(qout);
        const f4* attrs4 = reinterpret_cast<const f4*>(attrs);

        // rows 0..31: finalize 16-chunk column sums from partial
        for (int s = tid; s < 32 * 16; s += 256) {   // 2 iters
            const int row = s >> 4;
            const int cf  = s & 15;
            f4 sum = (f4)0.f;
#pragma unroll
            for (int c = 0; c < CHUNKS_OUT; ++c)
                sum += part4[(size_t)(row * CHUNKS_OUT + c) * 512 + cq + cf];
            f4 q;
            q.x = 1.f - __expf(-sum.x); q.y = 1.f - __expf(-sum.y);
            q.z = 1.f - __expf(-sum.z); q.w = 1.f - __expf(-sum.w);
            *reinterpret_cast<f4*>(&qt[row][cf * 4]) = q;
        }
        // rows 32..63: A's row-sum results (already 1-exp form)
        for (int s = tid; s < 32 * 16; s += 256) {   // 2 iters
            const int row = s >> 4;
            const int cf  = s & 15;
            *reinterpret_cast<f4*>(&qt[32 + row][cf * 4]) =
                qout4[(size_t)(32 + row) * 512 + cq + cf];
        }
        // rows 64..71: attributes
        if (tid < 8 * 16) {
            const int row = tid >> 4;
            const int cf  = tid & 15;
            f4 v = attrs4[(size_t)row * 512 + cq + cf];
            f4 q;
            q.x = 1.f - __expf(-2.f * v.x); q.y = 1.f - __expf(-2.f * v.y);
            q.z = 1.f - __expf(-2.f * v.z); q.w = 1.f - __expf(-2.f * v.w);
            *reinterpret_cast<f4*>(&qt[64 + row][cf * 4]) = q;
        }
        __syncthreads();

        // per-thread softmax over k for w = tid
        const int w = tid;
        float m = W[w];
#pragma unroll
        for (int k = 1; k < NK; ++k) m = fmaxf(m, W[k * WIDTH + w]);
        float ssum = 0.f;
#pragma unroll
        for (int k = 0; k < NK; ++k) ssum += __expf(W[k * WIDTH + w] - m);
        const float inv = 1.f / ssum;

        // k-loop: acc[16] f4 covers the 64-col slice for this w
        f4 acc[16];
#pragma unroll
        for (int i = 0; i < 16; ++i) acc[i] = (f4)0.f;
        for (int k = 0; k < NK; ++k) {
            const float s = __expf(W[k * WIDTH + w] - m) * inv;
            const f4* qrow = reinterpret_cast<const f4*>(&qt[k][0]);
#pragma unroll
            for (int i = 0; i < 16; ++i) acc[i] += s * qrow[i];
        }
        f4* o4 = reinterpret_cast<f4*>(out + (size_t)w * NENT + c0);
#pragma unroll
        for (int i = 0; i < 16; ++i) o4[i] = acc[i];
    } else {
        // ---------------- finalize block (old kernel B, minus softmax) ---
        const int idx = (b - MM_BLOCKS) * 256 + tid;   // over (32+8)*2048
        const int row = idx >> 11;
        const int n   = idx & (NENT - 1);
        if (row < NREL) {
            float s = 0.f;
#pragma unroll
            for (int c = 0; c < CHUNKS_OUT; ++c) // 16 independent loads
                s += partial[((size_t)(row * CHUNKS_OUT + c) << 11) + n];
            qout[((size_t)row << 11) + n] = 1.f - __expf(-s);
        } else {
            const int a = row - NREL;
            float v = attrs[((size_t)a << 11) + n];
            qout[((size_t)(2 * NREL + a) << 11) + n] = 1.f - __expf(-2.f * v);
        }
    }
}

extern "C" void kernel_launch(void* const* d_in, const int* in_sizes, int n_in,
                              void* d_out, int out_size, void* d_ws, size_t ws_size,
                              hipStream_t stream)
{
    const float* db    = (const float*)d_in[0];  // [32][2048][2048]
    const float* attrs = (const float*)d_in[1];  // [8][2048]
    const float* W     = (const float*)d_in[2];  // [72][256]

    float* out   = (float*)d_out;                    // [256][2048]
    float* quant = out + (size_t)WIDTH * NENT;       // [72][2048]

    float* partial = (float*)d_ws;                   // [512][2048] (4MB)

    reduce_db_kernel<<<NREL * CHUNKS_OUT, 256, 0, stream>>>(
        db, quant, partial, 8, SUBS);
    tail_kernel<<<MM_BLOCKS + FIN_BLOCKS, 256, 0, stream>>>(
        partial, attrs, W, quant, out);
}

// Round 9
// 100.630 us; speedup vs baseline: 1.1605x; 1.1605x over previous
//
#include <hip/hip_runtime.h>
#include <math.h>

#define NREL  32
#define NENT  2048
#define NATTR 8
#define WIDTH 256
#define NK    (2 * NREL + NATTR)   // 72
#define CHUNKS_OUT 16              // partial rows per relation
#define SUBS  4                    // sub-chunks (32 rows) per block

typedef float f4 __attribute__((ext_vector_type(4)));

// ---------------------------------------------------------------------------
// Kernel A: one pass over database — BYTE-IDENTICAL to the 100.2us R7 kernel.
// Non-temporal db reads (zero-reuse 512MB stream), row sums via transposed
// LDS, acc[8] column partials in registers -> partial[bx].
// ---------------------------------------------------------------------------
__global__ __launch_bounds__(256) void reduce_db_kernel(
    const float* __restrict__ db,
    float* __restrict__ qout,        // quantified region [72][2048]
    float* __restrict__ partial,     // [NREL*CHUNKS_OUT][2048]
    int rowsPerWave,                 // = 8  (runtime)
    int nSubs)                       // = 4  (runtime)
{
    const int bx   = blockIdx.x;
    const int r    = bx >> 4;              // / CHUNKS_OUT
    const int cOut = bx & (CHUNKS_OUT - 1);
    const int tid  = threadIdx.x;
    const int wave = tid >> 6;
    const int lane = tid & 63;

    __shared__ __align__(16) float smem[4][NENT];        // 32KB, dual-purpose
    float (*rpart)[33] = reinterpret_cast<float(*)[33]>(&smem[0][0]); // [64][33]

    const size_t rowStride = NENT / 4;
    const f4* relBase = reinterpret_cast<const f4*>(db)
                      + (size_t)r * NENT * rowStride
                      + (size_t)(cOut * 128) * rowStride
                      + lane;

    f4 acc[8];
#pragma unroll
    for (int k = 0; k < 8; ++k) acc[k] = (f4)0.f;

    for (int sc = 0; sc < nSubs; ++sc) {
        const int i0 = sc * 32;                  // local row base
        const f4* base = relBase
                       + (size_t)(i0 + wave * rowsPerWave) * rowStride;

        for (int j = 0; j < rowsPerWave; j += 2) {
            const f4* rowA = base + (size_t)j * rowStride;
            const f4* rowB = rowA + rowStride;
            float rsA = 0.f, rsB = 0.f;
            // 16 independent NON-TEMPORAL float4 loads; no cross-lane ops
#pragma unroll
            for (int k = 0; k < 8; ++k) {
                f4 v = __builtin_nontemporal_load(rowA + k * 64);
                acc[k] += v;
                rsA += (v.x + v.y) + (v.z + v.w);
            }
#pragma unroll
            for (int k = 0; k < 8; ++k) {
                f4 v = __builtin_nontemporal_load(rowB + k * 64);
                acc[k] += v;
                rsB += (v.x + v.y) + (v.z + v.w);
            }
            rpart[lane][wave * rowsPerWave + j]     = rsA;
            rpart[lane][wave * rowsPerWave + j + 1] = rsB;
        }
        __syncthreads();

        // finish row sums for this sub-chunk: thread t -> (row, 8-lane seg)
        {
            const int row = tid >> 3;       // 0..31 (local)
            const int seg = tid & 7;
            float t = 0.f;
#pragma unroll
            for (int i = 0; i < 8; ++i) t += rpart[seg * 8 + i][row];
            t += __shfl_xor(t, 1, 64);
            t += __shfl_xor(t, 2, 64);
            t += __shfl_xor(t, 4, 64);
            if (seg == 0)
                qout[(size_t)(NREL + r) * NENT + cOut * 128 + i0 + row] =
                    1.f - __expf(-t);
        }
        __syncthreads();   // rpart reads done before next sub-chunk rewrites
    }

    // block epilogue: combine the 4 waves' column partials (overlay rpart)
#pragma unroll
    for (int k = 0; k < 8; ++k)
        *reinterpret_cast<f4*>(&smem[wave][k * 256 + lane * 4]) = acc[k];
    __syncthreads();

    f4* part4 = reinterpret_cast<f4*>(partial) + (size_t)bx * rowStride;
    for (int g = tid; g < NENT / 4; g += 256) {
        f4 a0 = *reinterpret_cast<const f4*>(&smem[0][g * 4]);
        f4 a1 = *reinterpret_cast<const f4*>(&smem[1][g * 4]);
        f4 a2 = *reinterpret_cast<const f4*>(&smem[2][g * 4]);
        f4 a3 = *reinterpret_cast<const f4*>(&smem[3][g * 4]);
        part4[g] = (a0 + a1) + (a2 + a3);
    }
}

// ---------------------------------------------------------------------------
// Kernel T (merged tail, depends ONLY on A) — 448 blocks:
//  blocks 0..127  : R7's matmul tiles (32 w x 128 cols), made SELF-SUFFICIENT:
//                   quant rows 0..31 finalized from `partial` into LDS for
//                   this block's col-slice (8x redundant, ~32MB L2/L3 total),
//                   rows 32..63 from A's qout, rows 64..71 from attrs;
//                   32-w softmax computed per block from an LDS W-slice.
//                   Same parallelism & register budget as R7's C (the R8
//                   mistake was shrinking this to 32 blocks).
//  blocks 128..447: R7's finalize of the quantified output (rows 0..31 chunk
//                   sums + attr rows 64..71), running concurrently.
// ---------------------------------------------------------------------------
#define MM_BLOCKS  ((WIDTH / 32) * (NENT / 128))   // 128
#define FIN_BLOCKS ((NREL + NATTR) * NENT / 256)   // 320

__global__ __launch_bounds__(256) void tail_kernel(
    const float* __restrict__ partial,
    const float* __restrict__ attrs,
    const float* __restrict__ W,
    float* __restrict__ qout,
    float* __restrict__ out)
{
    const int b   = blockIdx.x;
    const int tid = threadIdx.x;

    if (b < MM_BLOCKS) {
        // ------------- matmul tile: 32 w's x 128 cols --------------------
        __shared__ __align__(16) float qt[NK][132];  // 38KB (132=33*4, 16B ok)
        __shared__ float wsl[NK][33];                // 9.5KB W-slice / softmax
        const int wg = b >> 4;                 // 0..7
        const int cg = b & 15;                 // 0..15
        const int w0 = wg * 32;
        const int c0 = cg * 128;
        const int cq = c0 >> 2;                // first f4 col of slice

        const f4* part4  = reinterpret_cast<const f4*>(partial);
        const f4* qout4  = reinterpret_cast<const f4*>(qout);
        const f4* attrs4 = reinterpret_cast<const f4*>(attrs);

        // stage qt[72][128-col slice]  (9 iters of 256 threads)
        for (int i = tid; i < NK * 32; i += 256) {
            const int k  = i >> 5;
            const int cf = i & 31;
            f4 q;
            if (k < NREL) {
                f4 sum = (f4)0.f;
#pragma unroll
                for (int c = 0; c < CHUNKS_OUT; ++c)
                    sum += part4[(size_t)(k * CHUNKS_OUT + c) * 512 + cq + cf];
                q.x = 1.f - __expf(-sum.x); q.y = 1.f - __expf(-sum.y);
                q.z = 1.f - __expf(-sum.z); q.w = 1.f - __expf(-sum.w);
            } else if (k < 2 * NREL) {
                q = qout4[(size_t)k * 512 + cq + cf];   // A already finalized
            } else {
                f4 v = attrs4[(size_t)(k - 2 * NREL) * 512 + cq + cf];
                q.x = 1.f - __expf(-2.f * v.x); q.y = 1.f - __expf(-2.f * v.y);
                q.z = 1.f - __expf(-2.f * v.z); q.w = 1.f - __expf(-2.f * v.w);
            }
            *reinterpret_cast<f4*>(&qt[k][cf * 4]) = q;
        }
        // stage W slice [72][32] (coalesced 32-wide rows)
        for (int i = tid; i < NK * 32; i += 256) {
            const int k  = i >> 5;
            const int wl = i & 31;
            wsl[k][wl] = W[k * WIDTH + w0 + wl];
        }
        __syncthreads();

        // softmax over k for this block's 32 w's (LDS-resident, conflict-free)
        if (tid < 32) {
            const int wl = tid;
            float m = wsl[0][wl];
#pragma unroll
            for (int k = 1; k < NK; ++k) m = fmaxf(m, wsl[k][wl]);
            float s = 0.f;
            float e[NK];
#pragma unroll
            for (int k = 0; k < NK; ++k) { e[k] = __expf(wsl[k][wl] - m); s += e[k]; }
            const float inv = 1.f / s;
#pragma unroll
            for (int k = 0; k < NK; ++k) wsl[k][wl] = e[k] * inv;
        }
        __syncthreads();

        // compute: thread = (wl = tid>>3, 16-col group cl = (tid&7)*16)
        const int wl = tid >> 3;
        const int cl = (tid & 7) * 16;
        f4 a0 = (f4)0.f, a1 = (f4)0.f, a2 = (f4)0.f, a3 = (f4)0.f;
#pragma unroll 8
        for (int k = 0; k < NK; ++k) {
            const float s = wsl[k][wl];
            const f4* row = reinterpret_cast<const f4*>(&qt[k][cl]);
            f4 v0 = row[0], v1 = row[1], v2 = row[2], v3 = row[3];
            a0 += s * v0; a1 += s * v1; a2 += s * v2; a3 += s * v3;
        }
        f4* o4 = reinterpret_cast<f4*>(out + (size_t)(w0 + wl) * NENT + c0 + cl);
        o4[0] = a0; o4[1] = a1; o4[2] = a2; o4[3] = a3;
    } else {
        // ------------- finalize quantified output (old kernel B) ---------
        const int idx = (b - MM_BLOCKS) * 256 + tid;   // over (32+8)*2048
        const int row = idx >> 11;
        const int n   = idx & (NENT - 1);
        if (row < NREL) {
            float s = 0.f;
#pragma unroll
            for (int c = 0; c < CHUNKS_OUT; ++c) // 16 independent loads
                s += partial[((size_t)(row * CHUNKS_OUT + c) << 11) + n];
            qout[((size_t)row << 11) + n] = 1.f - __expf(-s);
        } else {
            const int a = row - NREL;
            float v = attrs[((size_t)a << 11) + n];
            qout[((size_t)(2 * NREL + a) << 11) + n] = 1.f - __expf(-2.f * v);
        }
    }
}

extern "C" void kernel_launch(void* const* d_in, const int* in_sizes, int n_in,
                              void* d_out, int out_size, void* d_ws, size_t ws_size,
                              hipStream_t stream)
{
    const float* db    = (const float*)d_in[0];  // [32][2048][2048]
    const float* attrs = (const float*)d_in[1];  // [8][2048]
    const float* W     = (const float*)d_in[2];  // [72][256]

    float* out   = (float*)d_out;                    // [256][2048]
    float* quant = out + (size_t)WIDTH * NENT;       // [72][2048]

    float* partial = (float*)d_ws;                   // [512][2048] (4MB)

    reduce_db_kernel<<<NREL * CHUNKS_OUT, 256, 0, stream>>>(
        db, quant, partial, 8, SUBS);
    tail_kernel<<<MM_BLOCKS + FIN_BLOCKS, 256, 0, stream>>>(
        partial, attrs, W, quant, out);
}

// Round 10
// 99.850 us; speedup vs baseline: 1.1696x; 1.0078x over previous
//
#include <hip/hip_runtime.h>
#include <math.h>

#define NREL  32
#define NENT  2048
#define NATTR 8
#define WIDTH 256
#define NK    (2 * NREL + NATTR)   // 72
#define CHUNKS_OUT 16              // partial rows per relation (128-row chunks)

typedef float f4 __attribute__((ext_vector_type(4)));

// ---------------------------------------------------------------------------
// Kernel A: one pass over database. Block = (relation r, 128-row chunk).
// Hot inner body BYTE-IDENTICAL to R7 (16 independent non-temporal float4
// loads per row-pair, acc[8] column partials, fire-and-forget LDS row
// partials). Changes vs R7: all row-sum finishing deferred to ONE end phase
// (syncs 9 -> 2; no per-sub-chunk stalls), rpart[64][129] (stride 129 =>
// (lane+row)%32 banking, exact 2-way = free) + separate 32KB combine buffer
// (66KB LDS total -> still 2 blocks/CU; grid 512 = 2/CU is grid-limited).
// ---------------------------------------------------------------------------
__global__ __launch_bounds__(256) void reduce_db_kernel(
    const float* __restrict__ db,
    float* __restrict__ qout,        // quantified region [72][2048]
    float* __restrict__ partial,     // [NREL*CHUNKS_OUT][2048]
    int rowsPerWave)                 // = 32 (runtime to forbid unrolling)
{
    const int bx   = blockIdx.x;
    const int r    = bx >> 4;              // / CHUNKS_OUT
    const int cOut = bx & (CHUNKS_OUT - 1);
    const int tid  = threadIdx.x;
    const int wave = tid >> 6;
    const int lane = tid & 63;

    __shared__ float rpart[64][129];                 // 33.0KB row partials
    __shared__ __align__(16) float csmem[4][NENT];   // 32KB column combine

    const size_t rowStride = NENT / 4;
    // wave owns 32 contiguous rows of this 128-row chunk
    const f4* base = reinterpret_cast<const f4*>(db)
                   + (size_t)r * NENT * rowStride
                   + (size_t)(cOut * 128 + wave * rowsPerWave) * rowStride
                   + lane;

    f4 acc[8];
#pragma unroll
    for (int k = 0; k < 8; ++k) acc[k] = (f4)0.f;

    for (int jj = 0; jj < rowsPerWave; jj += 2) {    // 16 iters, runtime bound
        const f4* rowA = base + (size_t)jj * rowStride;
        const f4* rowB = rowA + rowStride;
        float rsA = 0.f, rsB = 0.f;
        // 16 independent NON-TEMPORAL float4 loads; no cross-lane ops
#pragma unroll
        for (int k = 0; k < 8; ++k) {
            f4 v = __builtin_nontemporal_load(rowA + k * 64);
            acc[k] += v;
            rsA += (v.x + v.y) + (v.z + v.w);
        }
#pragma unroll
        for (int k = 0; k < 8; ++k) {
            f4 v = __builtin_nontemporal_load(rowB + k * 64);
            acc[k] += v;
            rsB += (v.x + v.y) + (v.z + v.w);
        }
        rpart[lane][wave * rowsPerWave + jj]     = rsA;
        rpart[lane][wave * rowsPerWave + jj + 1] = rsB;
    }
    __syncthreads();

    // single row-sum finish phase: thread t -> (row = t>>1, half = t&1)
    {
        const int row  = tid >> 1;       // 0..127
        const int half = tid & 1;
        float s = 0.f;
#pragma unroll
        for (int i = 0; i < 32; ++i) s += rpart[half * 32 + i][row];
        s += __shfl_xor(s, 1, 64);
        if (half == 0)
            qout[(size_t)(NREL + r) * NENT + cOut * 128 + row] =
                1.f - __expf(-s);
    }

    // combine the 4 waves' column partials (separate buffer, no sync needed
    // between rpart reads above and csmem writes below)
#pragma unroll
    for (int k = 0; k < 8; ++k)
        *reinterpret_cast<f4*>(&csmem[wave][k * 256 + lane * 4]) = acc[k];
    __syncthreads();

    f4* part4 = reinterpret_cast<f4*>(partial) + (size_t)bx * rowStride;
    for (int g = tid; g < NENT / 4; g += 256) {
        f4 a0 = *reinterpret_cast<const f4*>(&csmem[0][g * 4]);
        f4 a1 = *reinterpret_cast<const f4*>(&csmem[1][g * 4]);
        f4 a2 = *reinterpret_cast<const f4*>(&csmem[2][g * 4]);
        f4 a3 = *reinterpret_cast<const f4*>(&csmem[3][g * 4]);
        part4[g] = (a0 + a1) + (a2 + a3);
    }
}

// ---------------------------------------------------------------------------
// Kernel T (tail, depends only on A) — 128 matmul blocks ONLY:
// Block (wg 0..7, cg 0..15) = 32 w's x 128 cols. Stages qt[72][128]:
// rows 0..31 finalized from `partial` (16-chunk sums), rows 32..63 from A's
// qout, rows 64..71 from attrs. wg==0 blocks additionally WRITE quant rows
// 0..31 and 64..71 for their col-slice (replaces the old 320 finalize
// blocks; rows 32..63 already written by A). 32-w softmax per block via LDS.
// ---------------------------------------------------------------------------
#define MM_BLOCKS  ((WIDTH / 32) * (NENT / 128))   // 128

__global__ __launch_bounds__(256) void tail_kernel(
    const float* __restrict__ partial,
    const float* __restrict__ attrs,
    const float* __restrict__ W,
    float* __restrict__ qout,
    float* __restrict__ out)
{
    const int b   = blockIdx.x;
    const int tid = threadIdx.x;

    __shared__ __align__(16) float qt[NK][132];  // 38KB (132 = 33*4)
    __shared__ float wsl[NK][33];                // 9.5KB W-slice / softmax
    const int wg = b >> 4;                 // 0..7
    const int cg = b & 15;                 // 0..15
    const int w0 = wg * 32;
    const int c0 = cg * 128;
    const int cq = c0 >> 2;                // first f4 col of slice

    const f4* part4  = reinterpret_cast<const f4*>(partial);
    const f4* qout4  = reinterpret_cast<const f4*>(qout);
    const f4* attrs4 = reinterpret_cast<const f4*>(attrs);
    f4*       qoutw4 = reinterpret_cast<f4*>(qout);

    // stage qt[72][128-col slice]  (9 iters of 256 threads)
    for (int i = tid; i < NK * 32; i += 256) {
        const int k  = i >> 5;
        const int cf = i & 31;
        f4 q;
        if (k < NREL) {
            f4 sum = (f4)0.f;
#pragma unroll
            for (int c = 0; c < CHUNKS_OUT; ++c)
                sum += part4[(size_t)(k * CHUNKS_OUT + c) * 512 + cq + cf];
            q.x = 1.f - __expf(-sum.x); q.y = 1.f - __expf(-sum.y);
            q.z = 1.f - __expf(-sum.z); q.w = 1.f - __expf(-sum.w);
            if (wg == 0) qoutw4[(size_t)k * 512 + cq + cf] = q;
        } else if (k < 2 * NREL) {
            q = qout4[(size_t)k * 512 + cq + cf];   // A already finalized
        } else {
            f4 v = attrs4[(size_t)(k - 2 * NREL) * 512 + cq + cf];
            q.x = 1.f - __expf(-2.f * v.x); q.y = 1.f - __expf(-2.f * v.y);
            q.z = 1.f - __expf(-2.f * v.z); q.w = 1.f - __expf(-2.f * v.w);
            if (wg == 0) qoutw4[(size_t)k * 512 + cq + cf] = q;
        }
        *reinterpret_cast<f4*>(&qt[k][cf * 4]) = q;
    }
    // stage W slice [72][32] (coalesced 32-wide rows)
    for (int i = tid; i < NK * 32; i += 256) {
        const int k  = i >> 5;
        const int wl = i & 31;
        wsl[k][wl] = W[k * WIDTH + w0 + wl];
    }
    __syncthreads();

    // softmax over k for this block's 32 w's (LDS-resident, conflict-free)
    if (tid < 32) {
        const int wl = tid;
        float m = wsl[0][wl];
#pragma unroll
        for (int k = 1; k < NK; ++k) m = fmaxf(m, wsl[k][wl]);
        float s = 0.f;
        float e[NK];
#pragma unroll
        for (int k = 0; k < NK; ++k) { e[k] = __expf(wsl[k][wl] - m); s += e[k]; }
        const float inv = 1.f / s;
#pragma unroll
        for (int k = 0; k < NK; ++k) wsl[k][wl] = e[k] * inv;
    }
    __syncthreads();

    // compute: thread = (wl = tid>>3, 16-col group cl = (tid&7)*16)
    const int wl = tid >> 3;
    const int cl = (tid & 7) * 16;
    f4 a0 = (f4)0.f, a1 = (f4)0.f, a2 = (f4)0.f, a3 = (f4)0.f;
#pragma unroll 8
    for (int k = 0; k < NK; ++k) {
        const float s = wsl[k][wl];
        const f4* row = reinterpret_cast<const f4*>(&qt[k][cl]);
        f4 v0 = row[0], v1 = row[1], v2 = row[2], v3 = row[3];
        a0 += s * v0; a1 += s * v1; a2 += s * v2; a3 += s * v3;
    }
    f4* o4 = reinterpret_cast<f4*>(out + (size_t)(w0 + wl) * NENT + c0 + cl);
    o4[0] = a0; o4[1] = a1; o4[2] = a2; o4[3] = a3;
}

extern "C" void kernel_launch(void* const* d_in, const int* in_sizes, int n_in,
                              void* d_out, int out_size, void* d_ws, size_t ws_size,
                              hipStream_t stream)
{
    const float* db    = (const float*)d_in[0];  // [32][2048][2048]
    const float* attrs = (const float*)d_in[1];  // [8][2048]
    const float* W     = (const float*)d_in[2];  // [72][256]

    float* out   = (float*)d_out;                    // [256][2048]
    float* quant = out + (size_t)WIDTH * NENT;       // [72][2048]

    float* partial = (float*)d_ws;                   // [512][2048] (4MB)

    reduce_db_kernel<<<NREL * CHUNKS_OUT, 256, 0, stream>>>(
        db, quant, partial, 32);
    tail_kernel<<<MM_BLOCKS, 256, 0, stream>>>(
        partial, attrs, W, quant, out);
}

// Round 11
// 94.678 us; speedup vs baseline: 1.2334x; 1.0546x over previous
//
#include <hip/hip_runtime.h>
#include <math.h>

#define NREL  32
#define NENT  2048
#define NATTR 8
#define WIDTH 256
#define NK    (2 * NREL + NATTR)   // 72
#define CHUNKS_OUT 16              // partial rows per relation (128-row chunks)

typedef float f4 __attribute__((ext_vector_type(4)));

// ---------------------------------------------------------------------------
// Kernel A: one pass over database — BYTE-IDENTICAL to the 99.8us R10 kernel.
// Non-temporal db reads; fire-and-forget LDS row partials (rpart[64][129],
// (lane+row)%32 = exact 2-way banking); single deferred row-sum finish; 32KB
// column-combine buffer; 2 syncs total. A is NOT occupancy-limited (R7 5/CU
// == R10 2/CU) — it runs at ~5.8 TB/s, the NT streaming-read ceiling.
// ---------------------------------------------------------------------------
__global__ __launch_bounds__(256) void reduce_db_kernel(
    const float* __restrict__ db,
    float* __restrict__ qout,        // quantified region [72][2048]
    float* __restrict__ partial,     // [NREL*CHUNKS_OUT][2048]
    int rowsPerWave)                 // = 32 (runtime to forbid unrolling)
{
    const int bx   = blockIdx.x;
    const int r    = bx >> 4;              // / CHUNKS_OUT
    const int cOut = bx & (CHUNKS_OUT - 1);
    const int tid  = threadIdx.x;
    const int wave = tid >> 6;
    const int lane = tid & 63;

    __shared__ float rpart[64][129];                 // 33.0KB row partials
    __shared__ __align__(16) float csmem[4][NENT];   // 32KB column combine

    const size_t rowStride = NENT / 4;
    // wave owns 32 contiguous rows of this 128-row chunk
    const f4* base = reinterpret_cast<const f4*>(db)
                   + (size_t)r * NENT * rowStride
                   + (size_t)(cOut * 128 + wave * rowsPerWave) * rowStride
                   + lane;

    f4 acc[8];
#pragma unroll
    for (int k = 0; k < 8; ++k) acc[k] = (f4)0.f;

    for (int jj = 0; jj < rowsPerWave; jj += 2) {    // 16 iters, runtime bound
        const f4* rowA = base + (size_t)jj * rowStride;
        const f4* rowB = rowA + rowStride;
        float rsA = 0.f, rsB = 0.f;
        // 16 independent NON-TEMPORAL float4 loads; no cross-lane ops
#pragma unroll
        for (int k = 0; k < 8; ++k) {
            f4 v = __builtin_nontemporal_load(rowA + k * 64);
            acc[k] += v;
            rsA += (v.x + v.y) + (v.z + v.w);
        }
#pragma unroll
        for (int k = 0; k < 8; ++k) {
            f4 v = __builtin_nontemporal_load(rowB + k * 64);
            acc[k] += v;
            rsB += (v.x + v.y) + (v.z + v.w);
        }
        rpart[lane][wave * rowsPerWave + jj]     = rsA;
        rpart[lane][wave * rowsPerWave + jj + 1] = rsB;
    }
    __syncthreads();

    // single row-sum finish phase: thread t -> (row = t>>1, half = t&1)
    {
        const int row  = tid >> 1;       // 0..127
        const int half = tid & 1;
        float s = 0.f;
#pragma unroll
        for (int i = 0; i < 32; ++i) s += rpart[half * 32 + i][row];
        s += __shfl_xor(s, 1, 64);
        if (half == 0)
            qout[(size_t)(NREL + r) * NENT + cOut * 128 + row] =
                1.f - __expf(-s);
    }

    // combine the 4 waves' column partials (separate buffer, no extra sync)
#pragma unroll
    for (int k = 0; k < 8; ++k)
        *reinterpret_cast<f4*>(&csmem[wave][k * 256 + lane * 4]) = acc[k];
    __syncthreads();

    f4* part4 = reinterpret_cast<f4*>(partial) + (size_t)bx * rowStride;
    for (int g = tid; g < NENT / 4; g += 256) {
        f4 a0 = *reinterpret_cast<const f4*>(&csmem[0][g * 4]);
        f4 a1 = *reinterpret_cast<const f4*>(&csmem[1][g * 4]);
        f4 a2 = *reinterpret_cast<const f4*>(&csmem[2][g * 4]);
        f4 a3 = *reinterpret_cast<const f4*>(&csmem[3][g * 4]);
        part4[g] = (a0 + a1) + (a2 + a3);
    }
}

// ---------------------------------------------------------------------------
// Kernel T (tail, depends only on A) — 256 blocks (was 128: half the chip
// sat idle). Block (wg 0..7, cg 0..31) = 32 w's x 64 cols. Stages qt[72][64]:
// rows 0..31 finalized from `partial` (16-chunk sums), rows 32..63 from A's
// qout, rows 64..71 from attrs. wg==0 blocks write quant rows 0..31 / 64..71
// for their col-slice. 32-w softmax per block via LDS. Same total partial
// traffic (8x wg redundancy unchanged); per-thread work halved (2 f4 accs).
// LDS ~29KB.
// ---------------------------------------------------------------------------
#define MM_BLOCKS  ((WIDTH / 32) * (NENT / 64))    // 256

__global__ __launch_bounds__(256) void tail_kernel(
    const float* __restrict__ partial,
    const float* __restrict__ attrs,
    const float* __restrict__ W,
    float* __restrict__ qout,
    float* __restrict__ out)
{
    const int b   = blockIdx.x;
    const int tid = threadIdx.x;

    __shared__ __align__(16) float qt[NK][68];   // 19.1KB (68 = 17*4)
    __shared__ float wsl[NK][33];                // 9.5KB W-slice / softmax
    const int wg = b >> 5;                 // 0..7
    const int cg = b & 31;                 // 0..31
    const int w0 = wg * 32;
    const int c0 = cg * 64;
    const int cq = c0 >> 2;                // first f4 col of slice

    const f4* part4  = reinterpret_cast<const f4*>(partial);
    const f4* qout4  = reinterpret_cast<const f4*>(qout);
    const f4* attrs4 = reinterpret_cast<const f4*>(attrs);
    f4*       qoutw4 = reinterpret_cast<f4*>(qout);

    // stage qt[72][64-col slice]  (4.5 iters of 256 threads)
    for (int i = tid; i < NK * 16; i += 256) {
        const int k  = i >> 4;
        const int cf = i & 15;
        f4 q;
        if (k < NREL) {
            f4 sum = (f4)0.f;
#pragma unroll
            for (int c = 0; c < CHUNKS_OUT; ++c)
                sum += part4[(size_t)(k * CHUNKS_OUT + c) * 512 + cq + cf];
            q.x = 1.f - __expf(-sum.x); q.y = 1.f - __expf(-sum.y);
            q.z = 1.f - __expf(-sum.z); q.w = 1.f - __expf(-sum.w);
            if (wg == 0) qoutw4[(size_t)k * 512 + cq + cf] = q;
        } else if (k < 2 * NREL) {
            q = qout4[(size_t)k * 512 + cq + cf];   // A already finalized
        } else {
            f4 v = attrs4[(size_t)(k - 2 * NREL) * 512 + cq + cf];
            q.x = 1.f - __expf(-2.f * v.x); q.y = 1.f - __expf(-2.f * v.y);
            q.z = 1.f - __expf(-2.f * v.z); q.w = 1.f - __expf(-2.f * v.w);
            if (wg == 0) qoutw4[(size_t)(k) * 512 + cq + cf] = q;
        }
        *reinterpret_cast<f4*>(&qt[k][cf * 4]) = q;
    }
    // stage W slice [72][32] (coalesced 32-wide rows)
    for (int i = tid; i < NK * 32; i += 256) {
        const int k  = i >> 5;
        const int wl = i & 31;
        wsl[k][wl] = W[k * WIDTH + w0 + wl];
    }
    __syncthreads();

    // softmax over k for this block's 32 w's (LDS-resident, conflict-free)
    if (tid < 32) {
        const int wl = tid;
        float m = wsl[0][wl];
#pragma unroll
        for (int k = 1; k < NK; ++k) m = fmaxf(m, wsl[k][wl]);
        float s = 0.f;
        float e[NK];
#pragma unroll
        for (int k = 0; k < NK; ++k) { e[k] = __expf(wsl[k][wl] - m); s += e[k]; }
        const float inv = 1.f / s;
#pragma unroll
        for (int k = 0; k < NK; ++k) wsl[k][wl] = e[k] * inv;
    }
    __syncthreads();

    // compute: thread = (wl = tid>>3, 8-col group cl = (tid&7)*8)
    const int wl = tid >> 3;
    const int cf = (tid & 7) * 2;          // f4 index within slice
    f4 a0 = (f4)0.f, a1 = (f4)0.f;
#pragma unroll 8
    for (int k = 0; k < NK; ++k) {
        const float s = wsl[k][wl];
        const f4* row = reinterpret_cast<const f4*>(&qt[k][0]);
        a0 += s * row[cf];
        a1 += s * row[cf + 1];
    }
    f4* o4 = reinterpret_cast<f4*>(out + (size_t)(w0 + wl) * NENT + c0) + cf;
    o4[0] = a0;
    o4[1] = a1;
}

extern "C" void kernel_launch(void* const* d_in, const int* in_sizes, int n_in,
                              void* d_out, int out_size, void* d_ws, size_t ws_size,
                              hipStream_t stream)
{
    const float* db    = (const float*)d_in[0];  // [32][2048][2048]
    const float* attrs = (const float*)d_in[1];  // [8][2048]
    const float* W     = (const float*)d_in[2];  // [72][256]

    float* out   = (float*)d_out;                    // [256][2048]
    float* quant = out + (size_t)WIDTH * NENT;       // [72][2048]

    float* partial = (float*)d_ws;                   // [512][2048] (4MB)

    reduce_db_kernel<<<NREL * CHUNKS_OUT, 256, 0, stream>>>(
        db, quant, partial, 32);
    tail_kernel<<<MM_BLOCKS, 256, 0, stream>>>(
        partial, attrs, W, quant, out);
}